// Round 2
// baseline (331.000 us; speedup 1.0000x reference)
//
#include <hip/hip_runtime.h>

#define N_PTS 4096
#define D_EMB 64
#define TILE  128
#define KH    32   // K staged in halves

// ---------------------------------------------------------------------------
// Row squared-norms: one wave per row, coalesced, shuffle reduce.
// ---------------------------------------------------------------------------
__global__ void row_norms_kernel(const float* __restrict__ mapping,
                                 float* __restrict__ nrm) {
  const int row = blockIdx.x;
  const int l = threadIdx.x;          // 0..63
  float v = mapping[row * D_EMB + l];
  float s = v * v;
  #pragma unroll
  for (int off = 32; off > 0; off >>= 1) s += __shfl_down(s, off);
  if (l == 0) nrm[row] = s;
}

// ---------------------------------------------------------------------------
// Fused pairwise-distance + distortion partial sums.
// 256 threads -> 128x128 tile, 8x8 per thread (rows ra+8m, cols cb+8n).
// K staged in two 32-wide halves: LDS = 2 * 128*32*4 = 32 KB -> 5 blocks/CU
// (vs 64 KB -> 2 blocks/CU in R1, which left the kernel latency-bound at
// 2 waves/SIMD, VALUBusy 11.5%).
// XOR swizzle at float4 granularity (c4' = c4 ^ (r&7)): k-chunk reads are
// 8-way-broadcast and bank-conflict-free; staging writes minimal.
// ---------------------------------------------------------------------------
__global__ __launch_bounds__(256, 5) void distortion_main(
    const float* __restrict__ mapping, const float* __restrict__ Dm,
    const float* __restrict__ nrm, double* __restrict__ acc) {
  __shared__ float As[TILE][KH];
  __shared__ float Bs[TILE][KH];

  const int t = threadIdx.x;
  const int i0 = blockIdx.y * TILE;
  const int j0 = blockIdx.x * TILE;

  const int w = t >> 6, l = t & 63;
  const int li = l >> 3, lj = l & 7;
  const int wi = w >> 1, wj = w & 1;
  const int ra = wi * 64 + li;  // thread rows: ra + 8m   ((ra+8m) & 7 == li)
  const int cb = wj * 64 + lj;  // thread cols: cb + 8n   ((cb+8n) & 7 == lj)

  float acc_t[8][8];
  #pragma unroll
  for (int m = 0; m < 8; ++m)
    #pragma unroll
    for (int n = 0; n < 8; ++n) acc_t[m][n] = 0.f;

  const float4* gA = (const float4*)(mapping + (size_t)i0 * D_EMB);
  const float4* gB = (const float4*)(mapping + (size_t)j0 * D_EMB);

  #pragma unroll
  for (int h = 0; h < 2; ++h) {
    if (h) __syncthreads();  // WAR: prior half's reads done before overwrite
    // ---- stage one 128x32 half per matrix (1024 float4 each, 256 thr x 4)
    #pragma unroll
    for (int i = 0; i < 4; ++i) {
      const int f = i * 256 + t;       // float4 slot within the 128x32 half
      const int r = f >> 3;            // row 0..127
      const int c4 = f & 7;            // float4-col 0..7
      const int sc4 = c4 ^ (r & 7);    // swizzle (bijective within row)
      const int g = r * (D_EMB / 4) + h * (KH / 4) + c4;  // global float4 idx
      *(float4*)&As[r][sc4 * 4] = gA[g];
      *(float4*)&Bs[r][sc4 * 4] = gB[g];
    }
    __syncthreads();

    for (int kc = 0; kc < KH / 4; ++kc) {   // 4 k-values per chunk
      float4 a[8], b[8];
      #pragma unroll
      for (int m = 0; m < 8; ++m)
        a[m] = *(const float4*)&As[ra + 8 * m][(kc ^ li) * 4];
      #pragma unroll
      for (int n = 0; n < 8; ++n)
        b[n] = *(const float4*)&Bs[cb + 8 * n][(kc ^ lj) * 4];
      #pragma unroll
      for (int m = 0; m < 8; ++m)
        #pragma unroll
        for (int n = 0; n < 8; ++n) {
          acc_t[m][n] = fmaf(a[m].x, b[n].x, acc_t[m][n]);
          acc_t[m][n] = fmaf(a[m].y, b[n].y, acc_t[m][n]);
          acc_t[m][n] = fmaf(a[m].z, b[n].z, acc_t[m][n]);
          acc_t[m][n] = fmaf(a[m].w, b[n].w, acc_t[m][n]);
        }
    }
  }

  // ---- epilogue: distances + distortion partial sums
  float rnA[8], rnB[8];
  #pragma unroll
  for (int m = 0; m < 8; ++m) rnA[m] = nrm[i0 + ra + 8 * m];
  #pragma unroll
  for (int n = 0; n < 8; ++n) rnB[n] = nrm[j0 + cb + 8 * n];

  float s1 = 0.f, s2 = 0.f, s3 = 0.f, s4 = 0.f;
  #pragma unroll
  for (int m = 0; m < 8; ++m) {
    const int gr = i0 + ra + 8 * m;
    const float* __restrict__ Drow = Dm + (size_t)gr * N_PTS;
    #pragma unroll
    for (int n = 0; n < 8; ++n) {
      const int gc = j0 + cb + 8 * n;
      const float Dv = Drow[gc];
      const float dot = acc_t[m][n];
      float sq = rnA[m] + rnB[n] - 2.f * dot;
      float dd = (sq > 0.f) ? __builtin_amdgcn_sqrtf(sq) : 0.f;
      const bool diag = (gr == gc);
      if (diag) dd = 0.f;                       // exact: ||x-x|| = 0
      const float denom = Dv + (diag ? 1.f : 0.f) + 1e-8f;
      const float rd = __builtin_amdgcn_rcpf(denom);
      const float av = dd * rd;                 // a = d/denom
      const float bv = Dv * rd;                 // b = D/denom
      s1 += av;                                 // sum a
      s2 = fmaf(av, av, s2);                    // sum a^2
      s3 = fmaf(av, bv, s3);                    // sum a*b
      s4 = fmaf(bv, bv, s4);                    // sum b^2
    }
  }

  // ---- reduction: wave shuffle, then f64 atomics (4 per wave)
  #pragma unroll
  for (int off = 32; off > 0; off >>= 1) {
    s1 += __shfl_down(s1, off);
    s2 += __shfl_down(s2, off);
    s3 += __shfl_down(s3, off);
    s4 += __shfl_down(s4, off);
  }
  if (l == 0) {
    atomicAdd(&acc[0], (double)s1);
    atomicAdd(&acc[1], (double)s2);
    atomicAdd(&acc[2], (double)s3);
    atomicAdd(&acc[3], (double)s4);
  }
}

// ---------------------------------------------------------------------------
// Final scalar: sum(dist) = s^2*S2 - 2 s S3 + S4, s = S1/S2.
// ---------------------------------------------------------------------------
__global__ void distortion_final(const double* __restrict__ acc,
                                 float* __restrict__ out) {
  const double S1 = acc[0], S2 = acc[1], S3 = acc[2], S4 = acc[3];
  const double s = S1 / S2;
  const double r = (s * s * S2 - 2.0 * s * S3 + S4) /
                   ((double)N_PTS * (double)N_PTS - (double)N_PTS);
  out[0] = (float)r;
}

extern "C" void kernel_launch(void* const* d_in, const int* in_sizes, int n_in,
                              void* d_out, int out_size, void* d_ws, size_t ws_size,
                              hipStream_t stream) {
  const float* mapping = (const float*)d_in[0];
  const float* Dm = (const float*)d_in[1];
  float* out = (float*)d_out;
  double* acc = (double*)d_ws;                    // 4 doubles
  float* nrm = (float*)((char*)d_ws + 64);        // 4096 f32 row norms

  hipMemsetAsync(d_ws, 0, 64, stream);            // zero accumulators each call
  row_norms_kernel<<<dim3(N_PTS), dim3(64), 0, stream>>>(mapping, nrm);
  distortion_main<<<dim3(N_PTS / TILE, N_PTS / TILE), dim3(256), 0, stream>>>(
      mapping, Dm, nrm, acc);
  distortion_final<<<1, 1, 0, stream>>>(acc, out);
}

// Round 3
// 241.797 us; speedup vs baseline: 1.3689x; 1.3689x over previous
//
#include <hip/hip_runtime.h>

#define N_PTS 4096
#define D_EMB 64
#define TILE  128
#define KH    32   // K staged in halves

// ---------------------------------------------------------------------------
// Row squared-norms: one wave per row, coalesced, shuffle reduce.
// ---------------------------------------------------------------------------
__global__ void row_norms_kernel(const float* __restrict__ mapping,
                                 float* __restrict__ nrm) {
  const int row = blockIdx.x;
  const int l = threadIdx.x;          // 0..63
  float v = mapping[row * D_EMB + l];
  float s = v * v;
  #pragma unroll
  for (int off = 32; off > 0; off >>= 1) s += __shfl_down(s, off);
  if (l == 0) nrm[row] = s;
}

// ---------------------------------------------------------------------------
// Fused pairwise-distance + distortion partial sums.
// 256 threads -> 128x128 tile, 8x8 per thread (rows ra+8m, cols cb+8n).
// LDS = 32 KB (K staged in two 32-wide halves) -> LDS cap 5 blocks/CU.
// __launch_bounds__(256, 4): VGPR cap 128. R2's (256,5) capped at 48 VGPRs
// and spilled the 64-register accumulator tile to scratch (WRITE_SIZE blew
// up to 507 MB, dur 331us). Live set needs ~90 VGPRs -> bound 4, not 5.
// XOR swizzle at float4 granularity (c4' = c4 ^ (r&7)): k-chunk reads are
// 8-way-broadcast and bank-conflict-free; staging writes minimal.
// ---------------------------------------------------------------------------
__global__ __launch_bounds__(256, 4) void distortion_main(
    const float* __restrict__ mapping, const float* __restrict__ Dm,
    const float* __restrict__ nrm, double* __restrict__ acc) {
  __shared__ float As[TILE][KH];
  __shared__ float Bs[TILE][KH];

  const int t = threadIdx.x;
  const int i0 = blockIdx.y * TILE;
  const int j0 = blockIdx.x * TILE;

  const int w = t >> 6, l = t & 63;
  const int li = l >> 3, lj = l & 7;
  const int wi = w >> 1, wj = w & 1;
  const int ra = wi * 64 + li;  // thread rows: ra + 8m   ((ra+8m) & 7 == li)
  const int cb = wj * 64 + lj;  // thread cols: cb + 8n   ((cb+8n) & 7 == lj)

  float acc_t[8][8];
  #pragma unroll
  for (int m = 0; m < 8; ++m)
    #pragma unroll
    for (int n = 0; n < 8; ++n) acc_t[m][n] = 0.f;

  const float4* gA = (const float4*)(mapping + (size_t)i0 * D_EMB);
  const float4* gB = (const float4*)(mapping + (size_t)j0 * D_EMB);

  #pragma unroll
  for (int h = 0; h < 2; ++h) {
    if (h) __syncthreads();  // WAR: prior half's reads done before overwrite
    // ---- stage one 128x32 half per matrix (1024 float4 each, 256 thr x 4)
    #pragma unroll
    for (int i = 0; i < 4; ++i) {
      const int f = i * 256 + t;       // float4 slot within the 128x32 half
      const int r = f >> 3;            // row 0..127
      const int c4 = f & 7;            // float4-col 0..7
      const int sc4 = c4 ^ (r & 7);    // swizzle (bijective within row)
      const int g = r * (D_EMB / 4) + h * (KH / 4) + c4;  // global float4 idx
      *(float4*)&As[r][sc4 * 4] = gA[g];
      *(float4*)&Bs[r][sc4 * 4] = gB[g];
    }
    __syncthreads();

    for (int kc = 0; kc < KH / 4; ++kc) {   // 4 k-values per chunk
      float4 a[8], b[8];
      #pragma unroll
      for (int m = 0; m < 8; ++m)
        a[m] = *(const float4*)&As[ra + 8 * m][(kc ^ li) * 4];
      #pragma unroll
      for (int n = 0; n < 8; ++n)
        b[n] = *(const float4*)&Bs[cb + 8 * n][(kc ^ lj) * 4];
      #pragma unroll
      for (int m = 0; m < 8; ++m)
        #pragma unroll
        for (int n = 0; n < 8; ++n) {
          acc_t[m][n] = fmaf(a[m].x, b[n].x, acc_t[m][n]);
          acc_t[m][n] = fmaf(a[m].y, b[n].y, acc_t[m][n]);
          acc_t[m][n] = fmaf(a[m].z, b[n].z, acc_t[m][n]);
          acc_t[m][n] = fmaf(a[m].w, b[n].w, acc_t[m][n]);
        }
    }
  }

  // ---- epilogue: distances + distortion partial sums
  float rnA[8], rnB[8];
  #pragma unroll
  for (int m = 0; m < 8; ++m) rnA[m] = nrm[i0 + ra + 8 * m];
  #pragma unroll
  for (int n = 0; n < 8; ++n) rnB[n] = nrm[j0 + cb + 8 * n];

  float s1 = 0.f, s2 = 0.f, s3 = 0.f, s4 = 0.f;
  #pragma unroll
  for (int m = 0; m < 8; ++m) {
    const int gr = i0 + ra + 8 * m;
    const float* __restrict__ Drow = Dm + (size_t)gr * N_PTS;
    #pragma unroll
    for (int n = 0; n < 8; ++n) {
      const int gc = j0 + cb + 8 * n;
      const float Dv = Drow[gc];
      const float dot = acc_t[m][n];
      float sq = rnA[m] + rnB[n] - 2.f * dot;
      float dd = (sq > 0.f) ? __builtin_amdgcn_sqrtf(sq) : 0.f;
      const bool diag = (gr == gc);
      if (diag) dd = 0.f;                       // exact: ||x-x|| = 0
      const float denom = Dv + (diag ? 1.f : 0.f) + 1e-8f;
      const float rd = __builtin_amdgcn_rcpf(denom);
      const float av = dd * rd;                 // a = d/denom
      const float bv = Dv * rd;                 // b = D/denom
      s1 += av;                                 // sum a
      s2 = fmaf(av, av, s2);                    // sum a^2
      s3 = fmaf(av, bv, s3);                    // sum a*b
      s4 = fmaf(bv, bv, s4);                    // sum b^2
    }
  }

  // ---- reduction: wave shuffle, then f64 atomics (4 per wave)
  #pragma unroll
  for (int off = 32; off > 0; off >>= 1) {
    s1 += __shfl_down(s1, off);
    s2 += __shfl_down(s2, off);
    s3 += __shfl_down(s3, off);
    s4 += __shfl_down(s4, off);
  }
  if (l == 0) {
    atomicAdd(&acc[0], (double)s1);
    atomicAdd(&acc[1], (double)s2);
    atomicAdd(&acc[2], (double)s3);
    atomicAdd(&acc[3], (double)s4);
  }
}

// ---------------------------------------------------------------------------
// Final scalar: sum(dist) = s^2*S2 - 2 s S3 + S4, s = S1/S2.
// ---------------------------------------------------------------------------
__global__ void distortion_final(const double* __restrict__ acc,
                                 float* __restrict__ out) {
  const double S1 = acc[0], S2 = acc[1], S3 = acc[2], S4 = acc[3];
  const double s = S1 / S2;
  const double r = (s * s * S2 - 2.0 * s * S3 + S4) /
                   ((double)N_PTS * (double)N_PTS - (double)N_PTS);
  out[0] = (float)r;
}

extern "C" void kernel_launch(void* const* d_in, const int* in_sizes, int n_in,
                              void* d_out, int out_size, void* d_ws, size_t ws_size,
                              hipStream_t stream) {
  const float* mapping = (const float*)d_in[0];
  const float* Dm = (const float*)d_in[1];
  float* out = (float*)d_out;
  double* acc = (double*)d_ws;                    // 4 doubles
  float* nrm = (float*)((char*)d_ws + 64);        // 4096 f32 row norms

  hipMemsetAsync(d_ws, 0, 64, stream);            // zero accumulators each call
  row_norms_kernel<<<dim3(N_PTS), dim3(64), 0, stream>>>(mapping, nrm);
  distortion_main<<<dim3(N_PTS / TILE, N_PTS / TILE), dim3(256), 0, stream>>>(
      mapping, Dm, nrm, acc);
  distortion_final<<<1, 1, 0, stream>>>(acc, out);
}

// Round 4
// 227.094 us; speedup vs baseline: 1.4575x; 1.0647x over previous
//
#include <hip/hip_runtime.h>

#define N_PTS 4096
#define D_EMB 64
#define TILE  128
#define KH    32   // K staged in halves

// ---------------------------------------------------------------------------
// Row squared-norms: one wave per row, coalesced, shuffle reduce.
// ---------------------------------------------------------------------------
__global__ void row_norms_kernel(const float* __restrict__ mapping,
                                 float* __restrict__ nrm) {
  const int row = blockIdx.x;
  const int l = threadIdx.x;          // 0..63
  float v = mapping[row * D_EMB + l];
  float s = v * v;
  #pragma unroll
  for (int off = 32; off > 0; off >>= 1) s += __shfl_down(s, off);
  if (l == 0) nrm[row] = s;
}

// ---------------------------------------------------------------------------
// Fused pairwise-distance + distortion partial sums.
// 256 threads -> 128x128 tile, 8x8 per thread (rows ra+8m, cols cb+8n).
// LDS = 32 KB (K staged in two 32-wide halves) -> LDS cap 5 blocks/CU.
//
// launch_bounds history (this exact inner loop):
//   (256,2) -> 88 VGPR, no spill   (R1: 216us, but 64KB LDS capped 2 blk/CU)
//   (256,5) -> 48 VGPR, huge spill (R2: 331us, WRITE_SIZE 507MB)
//   (256,4) -> 64 VGPR, spill      (R3: 242us, WRITE_SIZE 22MB)
// => keep (256,2): compiler-chosen 88 VGPR (floor(512/88)=5 waves/SIMD),
//    occupancy now controlled by the 32KB LDS -> 4-5 blocks/CU, grid=1024
//    fully co-resident at 4 blocks/CU.
//
// XOR swizzle at float4 granularity (c4' = c4 ^ (r&7)): k-chunk reads are
// 8-way-broadcast and bank-conflict-free; staging writes minimal.
// ---------------------------------------------------------------------------
__global__ __launch_bounds__(256, 2) void distortion_main(
    const float* __restrict__ mapping, const float* __restrict__ Dm,
    const float* __restrict__ nrm, double* __restrict__ acc) {
  __shared__ float As[TILE][KH];
  __shared__ float Bs[TILE][KH];

  const int t = threadIdx.x;
  const int i0 = blockIdx.y * TILE;
  const int j0 = blockIdx.x * TILE;

  const int w = t >> 6, l = t & 63;
  const int li = l >> 3, lj = l & 7;
  const int wi = w >> 1, wj = w & 1;
  const int ra = wi * 64 + li;  // thread rows: ra + 8m   ((ra+8m) & 7 == li)
  const int cb = wj * 64 + lj;  // thread cols: cb + 8n   ((cb+8n) & 7 == lj)

  float acc_t[8][8];
  #pragma unroll
  for (int m = 0; m < 8; ++m)
    #pragma unroll
    for (int n = 0; n < 8; ++n) acc_t[m][n] = 0.f;

  const float4* gA = (const float4*)(mapping + (size_t)i0 * D_EMB);
  const float4* gB = (const float4*)(mapping + (size_t)j0 * D_EMB);

  #pragma unroll
  for (int h = 0; h < 2; ++h) {
    if (h) __syncthreads();  // WAR: prior half's reads done before overwrite
    // ---- stage one 128x32 half per matrix (1024 float4 each, 256 thr x 4)
    #pragma unroll
    for (int i = 0; i < 4; ++i) {
      const int f = i * 256 + t;       // float4 slot within the 128x32 half
      const int r = f >> 3;            // row 0..127
      const int c4 = f & 7;            // float4-col 0..7
      const int sc4 = c4 ^ (r & 7);    // swizzle (bijective within row)
      const int g = r * (D_EMB / 4) + h * (KH / 4) + c4;  // global float4 idx
      *(float4*)&As[r][sc4 * 4] = gA[g];
      *(float4*)&Bs[r][sc4 * 4] = gB[g];
    }
    __syncthreads();

    for (int kc = 0; kc < KH / 4; ++kc) {   // 4 k-values per chunk
      float4 a[8], b[8];
      #pragma unroll
      for (int m = 0; m < 8; ++m)
        a[m] = *(const float4*)&As[ra + 8 * m][(kc ^ li) * 4];
      #pragma unroll
      for (int n = 0; n < 8; ++n)
        b[n] = *(const float4*)&Bs[cb + 8 * n][(kc ^ lj) * 4];
      #pragma unroll
      for (int m = 0; m < 8; ++m)
        #pragma unroll
        for (int n = 0; n < 8; ++n) {
          acc_t[m][n] = fmaf(a[m].x, b[n].x, acc_t[m][n]);
          acc_t[m][n] = fmaf(a[m].y, b[n].y, acc_t[m][n]);
          acc_t[m][n] = fmaf(a[m].z, b[n].z, acc_t[m][n]);
          acc_t[m][n] = fmaf(a[m].w, b[n].w, acc_t[m][n]);
        }
    }
  }

  // ---- epilogue: distances + distortion partial sums
  float rnA[8], rnB[8];
  #pragma unroll
  for (int m = 0; m < 8; ++m) rnA[m] = nrm[i0 + ra + 8 * m];
  #pragma unroll
  for (int n = 0; n < 8; ++n) rnB[n] = nrm[j0 + cb + 8 * n];

  float s1 = 0.f, s2 = 0.f, s3 = 0.f, s4 = 0.f;
  #pragma unroll
  for (int m = 0; m < 8; ++m) {
    const int gr = i0 + ra + 8 * m;
    const float* __restrict__ Drow = Dm + (size_t)gr * N_PTS;
    #pragma unroll
    for (int n = 0; n < 8; ++n) {
      const int gc = j0 + cb + 8 * n;
      const float Dv = Drow[gc];
      const float dot = acc_t[m][n];
      float sq = rnA[m] + rnB[n] - 2.f * dot;
      float dd = (sq > 0.f) ? __builtin_amdgcn_sqrtf(sq) : 0.f;
      const bool diag = (gr == gc);
      if (diag) dd = 0.f;                       // exact: ||x-x|| = 0
      const float denom = Dv + (diag ? 1.f : 0.f) + 1e-8f;
      const float rd = __builtin_amdgcn_rcpf(denom);
      const float av = dd * rd;                 // a = d/denom
      const float bv = Dv * rd;                 // b = D/denom
      s1 += av;                                 // sum a
      s2 = fmaf(av, av, s2);                    // sum a^2
      s3 = fmaf(av, bv, s3);                    // sum a*b
      s4 = fmaf(bv, bv, s4);                    // sum b^2
    }
  }

  // ---- reduction: wave shuffle, then f64 atomics (4 per wave)
  #pragma unroll
  for (int off = 32; off > 0; off >>= 1) {
    s1 += __shfl_down(s1, off);
    s2 += __shfl_down(s2, off);
    s3 += __shfl_down(s3, off);
    s4 += __shfl_down(s4, off);
  }
  if (l == 0) {
    atomicAdd(&acc[0], (double)s1);
    atomicAdd(&acc[1], (double)s2);
    atomicAdd(&acc[2], (double)s3);
    atomicAdd(&acc[3], (double)s4);
  }
}

// ---------------------------------------------------------------------------
// Final scalar: sum(dist) = s^2*S2 - 2 s S3 + S4, s = S1/S2.
// ---------------------------------------------------------------------------
__global__ void distortion_final(const double* __restrict__ acc,
                                 float* __restrict__ out) {
  const double S1 = acc[0], S2 = acc[1], S3 = acc[2], S4 = acc[3];
  const double s = S1 / S2;
  const double r = (s * s * S2 - 2.0 * s * S3 + S4) /
                   ((double)N_PTS * (double)N_PTS - (double)N_PTS);
  out[0] = (float)r;
}

extern "C" void kernel_launch(void* const* d_in, const int* in_sizes, int n_in,
                              void* d_out, int out_size, void* d_ws, size_t ws_size,
                              hipStream_t stream) {
  const float* mapping = (const float*)d_in[0];
  const float* Dm = (const float*)d_in[1];
  float* out = (float*)d_out;
  double* acc = (double*)d_ws;                    // 4 doubles
  float* nrm = (float*)((char*)d_ws + 64);        // 4096 f32 row norms

  hipMemsetAsync(d_ws, 0, 64, stream);            // zero accumulators each call
  row_norms_kernel<<<dim3(N_PTS), dim3(64), 0, stream>>>(mapping, nrm);
  distortion_main<<<dim3(N_PTS / TILE, N_PTS / TILE), dim3(256), 0, stream>>>(
      mapping, Dm, nrm, acc);
  distortion_final<<<1, 1, 0, stream>>>(acc, out);
}

// Round 5
// 50.198 us; speedup vs baseline: 6.5939x; 4.5240x over previous
//
#include <hip/hip_runtime.h>

#define N_PTS 4096
#define D_EMB 64
#define TILE  128
#define KH    32                     // K staged in halves
#define NWAVE ((N_PTS / TILE) * (N_PTS / TILE) * 4)   // 4096 waves in main grid

// ---------------------------------------------------------------------------
// Row squared-norms: one wave per row, coalesced, shuffle reduce.
// ---------------------------------------------------------------------------
__global__ void row_norms_kernel(const float* __restrict__ mapping,
                                 float* __restrict__ nrm) {
  const int row = blockIdx.x;
  const int l = threadIdx.x;          // 0..63
  float v = mapping[row * D_EMB + l];
  float s = v * v;
  #pragma unroll
  for (int off = 32; off > 0; off >>= 1) s += __shfl_down(s, off);
  if (l == 0) nrm[row] = s;
}

// ---------------------------------------------------------------------------
// Fused pairwise-distance + distortion partial sums.
// 256 threads -> 128x128 tile, 8x8 per thread (rows ra+8m, cols cb+8n).
// LDS = 32 KB (K staged in two 32-wide halves).
// launch_bounds (256,2): compiler picks 72-88 VGPR, no spill (R2/R3 showed
// tighter bounds force catastrophic accumulator spills).
//
// R4 evidence: dur invariant at ~218us across 2 and ~4.4 blocks/CU, all
// pipes idle, warm replays (D fully L3-cached, 0.5MB fetch) identical
// => bottleneck was the 16384 same-line f64 atomicAdds (4/wave to one
// 32B line, ~32 cyc/atomic serialized at device scope).
// Fix: contention-free per-wave partial writes to part[4][NWAVE]; a tiny
// final kernel reduces them. No atomics anywhere.
// ---------------------------------------------------------------------------
__global__ __launch_bounds__(256, 2) void distortion_main(
    const float* __restrict__ mapping, const float* __restrict__ Dm,
    const float* __restrict__ nrm, double* __restrict__ part) {
  __shared__ float As[TILE][KH];
  __shared__ float Bs[TILE][KH];

  const int t = threadIdx.x;
  const int i0 = blockIdx.y * TILE;
  const int j0 = blockIdx.x * TILE;

  const int w = t >> 6, l = t & 63;
  const int li = l >> 3, lj = l & 7;
  const int wi = w >> 1, wj = w & 1;
  const int ra = wi * 64 + li;  // thread rows: ra + 8m   ((ra+8m) & 7 == li)
  const int cb = wj * 64 + lj;  // thread cols: cb + 8n   ((cb+8n) & 7 == lj)

  float acc_t[8][8];
  #pragma unroll
  for (int m = 0; m < 8; ++m)
    #pragma unroll
    for (int n = 0; n < 8; ++n) acc_t[m][n] = 0.f;

  const float4* gA = (const float4*)(mapping + (size_t)i0 * D_EMB);
  const float4* gB = (const float4*)(mapping + (size_t)j0 * D_EMB);

  #pragma unroll
  for (int h = 0; h < 2; ++h) {
    if (h) __syncthreads();  // WAR: prior half's reads done before overwrite
    // ---- stage one 128x32 half per matrix (1024 float4 each, 256 thr x 4)
    #pragma unroll
    for (int i = 0; i < 4; ++i) {
      const int f = i * 256 + t;       // float4 slot within the 128x32 half
      const int r = f >> 3;            // row 0..127
      const int c4 = f & 7;            // float4-col 0..7
      const int sc4 = c4 ^ (r & 7);    // swizzle (bijective within row)
      const int g = r * (D_EMB / 4) + h * (KH / 4) + c4;  // global float4 idx
      *(float4*)&As[r][sc4 * 4] = gA[g];
      *(float4*)&Bs[r][sc4 * 4] = gB[g];
    }
    __syncthreads();

    for (int kc = 0; kc < KH / 4; ++kc) {   // 4 k-values per chunk
      float4 a[8], b[8];
      #pragma unroll
      for (int m = 0; m < 8; ++m)
        a[m] = *(const float4*)&As[ra + 8 * m][(kc ^ li) * 4];
      #pragma unroll
      for (int n = 0; n < 8; ++n)
        b[n] = *(const float4*)&Bs[cb + 8 * n][(kc ^ lj) * 4];
      #pragma unroll
      for (int m = 0; m < 8; ++m)
        #pragma unroll
        for (int n = 0; n < 8; ++n) {
          acc_t[m][n] = fmaf(a[m].x, b[n].x, acc_t[m][n]);
          acc_t[m][n] = fmaf(a[m].y, b[n].y, acc_t[m][n]);
          acc_t[m][n] = fmaf(a[m].z, b[n].z, acc_t[m][n]);
          acc_t[m][n] = fmaf(a[m].w, b[n].w, acc_t[m][n]);
        }
    }
  }

  // ---- epilogue: distances + distortion partial sums
  float rnA[8], rnB[8];
  #pragma unroll
  for (int m = 0; m < 8; ++m) rnA[m] = nrm[i0 + ra + 8 * m];
  #pragma unroll
  for (int n = 0; n < 8; ++n) rnB[n] = nrm[j0 + cb + 8 * n];

  float s1 = 0.f, s2 = 0.f, s3 = 0.f, s4 = 0.f;
  #pragma unroll
  for (int m = 0; m < 8; ++m) {
    const int gr = i0 + ra + 8 * m;
    const float* __restrict__ Drow = Dm + (size_t)gr * N_PTS;
    #pragma unroll
    for (int n = 0; n < 8; ++n) {
      const int gc = j0 + cb + 8 * n;
      const float Dv = Drow[gc];
      const float dot = acc_t[m][n];
      float sq = rnA[m] + rnB[n] - 2.f * dot;
      float dd = (sq > 0.f) ? __builtin_amdgcn_sqrtf(sq) : 0.f;
      const bool diag = (gr == gc);
      if (diag) dd = 0.f;                       // exact: ||x-x|| = 0
      const float denom = Dv + (diag ? 1.f : 0.f) + 1e-8f;
      const float rd = __builtin_amdgcn_rcpf(denom);
      const float av = dd * rd;                 // a = d/denom
      const float bv = Dv * rd;                 // b = D/denom
      s1 += av;                                 // sum a
      s2 = fmaf(av, av, s2);                    // sum a^2
      s3 = fmaf(av, bv, s3);                    // sum a*b
      s4 = fmaf(bv, bv, s4);                    // sum b^2
    }
  }

  // ---- reduction: wave shuffle, then one contention-free write per wave
  #pragma unroll
  for (int off = 32; off > 0; off >>= 1) {
    s1 += __shfl_down(s1, off);
    s2 += __shfl_down(s2, off);
    s3 += __shfl_down(s3, off);
    s4 += __shfl_down(s4, off);
  }
  if (l == 0) {
    const int gw = ((blockIdx.y * gridDim.x + blockIdx.x) << 2) + w;
    part[0 * NWAVE + gw] = (double)s1;
    part[1 * NWAVE + gw] = (double)s2;
    part[2 * NWAVE + gw] = (double)s3;
    part[3 * NWAVE + gw] = (double)s4;
  }
}

// ---------------------------------------------------------------------------
// Reduce 4 x NWAVE partials; emit sum(dist) = s^2*S2 - 2 s S3 + S4, s=S1/S2.
// One block, 1024 threads (16 waves).
// ---------------------------------------------------------------------------
__global__ __launch_bounds__(1024) void distortion_final(
    const double* __restrict__ part, float* __restrict__ out) {
  __shared__ double red[16][4];
  const int t = threadIdx.x;
  double s[4];
  #pragma unroll
  for (int k = 0; k < 4; ++k) {
    double v = 0.0;
    #pragma unroll
    for (int c = 0; c < NWAVE / 1024; ++c) v += part[k * NWAVE + c * 1024 + t];
    s[k] = v;
  }
  #pragma unroll
  for (int off = 32; off > 0; off >>= 1)
    #pragma unroll
    for (int k = 0; k < 4; ++k) s[k] += __shfl_down(s[k], off);
  const int w = t >> 6, l = t & 63;
  if (l == 0) {
    #pragma unroll
    for (int k = 0; k < 4; ++k) red[w][k] = s[k];
  }
  __syncthreads();
  if (t == 0) {
    double S0 = 0, S1 = 0, S2 = 0, S3 = 0;
    #pragma unroll
    for (int ww = 0; ww < 16; ++ww) {
      S0 += red[ww][0]; S1 += red[ww][1]; S2 += red[ww][2]; S3 += red[ww][3];
    }
    const double sc = S0 / S1;
    const double r = (sc * sc * S1 - 2.0 * sc * S2 + S3) /
                     ((double)N_PTS * (double)N_PTS - (double)N_PTS);
    out[0] = (float)r;
  }
}

extern "C" void kernel_launch(void* const* d_in, const int* in_sizes, int n_in,
                              void* d_out, int out_size, void* d_ws, size_t ws_size,
                              hipStream_t stream) {
  const float* mapping = (const float*)d_in[0];
  const float* Dm = (const float*)d_in[1];
  float* out = (float*)d_out;
  float* nrm = (float*)d_ws;                          // 4096 f32 (16 KB)
  double* part = (double*)((char*)d_ws + 16384);      // 4 x 4096 f64 (128 KB)

  row_norms_kernel<<<dim3(N_PTS), dim3(64), 0, stream>>>(mapping, nrm);
  distortion_main<<<dim3(N_PTS / TILE, N_PTS / TILE), dim3(256), 0, stream>>>(
      mapping, Dm, nrm, part);
  distortion_final<<<1, 1024, 0, stream>>>(part, out);
}

// Round 6
// 42.348 us; speedup vs baseline: 7.8163x; 1.1854x over previous
//
#include <hip/hip_runtime.h>
#include <hip/hip_bf16.h>

#define N_PTS 4096
#define D_EMB 64
#define TILE  128
#define NWAVE ((N_PTS / TILE) * (N_PTS / TILE) * 4)   // 4096 waves in main grid

typedef __attribute__((ext_vector_type(8))) short bf16x8;  // 8 bf16 = 4 VGPR
typedef __attribute__((ext_vector_type(4))) float f32x4;   // MFMA 16x16 acc

// ---------------------------------------------------------------------------
// Split f32 -> bf16 hi + bf16 lo (x = hi + lo + O(2^-17)). Elementwise.
// ---------------------------------------------------------------------------
__global__ void split_kernel(const float* __restrict__ mapping,
                             ushort* __restrict__ Mhi,
                             ushort* __restrict__ Mlo) {
  const int i = blockIdx.x * 256 + threadIdx.x;
  const float x = mapping[i];
  __hip_bfloat16 h = __float2bfloat16(x);
  const float hf = __bfloat162float(h);
  __hip_bfloat16 lo = __float2bfloat16(x - hf);
  Mhi[i] = *reinterpret_cast<ushort*>(&h);
  Mlo[i] = *reinterpret_cast<ushort*>(&lo);
}

// ---------------------------------------------------------------------------
// Row squared-norms from the EXACT f32 mapping (norm precision unaffected
// by the bf16 split). One wave per row.
// ---------------------------------------------------------------------------
__global__ void row_norms_kernel(const float* __restrict__ mapping,
                                 float* __restrict__ nrm) {
  const int row = blockIdx.x;
  const int l = threadIdx.x;          // 0..63
  float v = mapping[row * D_EMB + l];
  float s = v * v;
  #pragma unroll
  for (int off = 32; off > 0; off >>= 1) s += __shfl_down(s, off);
  if (l == 0) nrm[row] = s;
}

// ---------------------------------------------------------------------------
// MFMA gram + fused distortion partial sums.
// dot = hi.hi + hi.lo + lo.hi  (lo.lo dropped: rel err ~2^-16; norms exact,
// diagonal exact -> scalar err ~1e-5 << 2e-2 threshold).
//
// 256 thr = 4 waves (2x2), 128x128 tile/block, 64x64 per wave as 4x4 MFMA
// tiles of 16x16, K=64 = 2 steps of 32. Fragments load DIRECTLY from global
// (no LDS, no barriers): mfma_f32_16x16x32_bf16 operand layout
//   A: lane l -> row l&15,  k = (l>>4)*8 + j   (8 contiguous bf16 = 16B)
//   B: lane l -> col l&15,  k = (l>>4)*8 + j   (same addressing: B = M^T)
//   C/D: col = lane&15, row = (lane>>4)*4 + reg   [verified m89 layout]
// Per-wave A/B panels are 16KB and L1/L2-resident; rows reused 32x across
// the block row/col -> L2.
//
// R5 lesson kept: per-wave contention-free partial writes (NO atomics).
// R2/R3 lesson kept: no min-waves launch_bounds arg (forced spills).
// ---------------------------------------------------------------------------
__global__ __launch_bounds__(256) void distortion_main(
    const ushort* __restrict__ Mhi, const ushort* __restrict__ Mlo,
    const float* __restrict__ Dm, const float* __restrict__ nrm,
    double* __restrict__ part) {
  const int t = threadIdx.x;
  const int w = t >> 6, l = t & 63;
  const int r16 = l & 15;        // row/col within 16x16 fragment
  const int kg = l >> 4;         // k-group 0..3
  const int wr = w >> 1, wc = w & 1;
  const int i0 = blockIdx.y * TILE + wr * 64;   // wave row base
  const int j0 = blockIdx.x * TILE + wc * 64;   // wave col base

  f32x4 acc[4][4] = {};          // acc[m][n]: output rows m*16+, cols n*16+

  #pragma unroll
  for (int ks = 0; ks < 2; ++ks) {
    const int koff = ks * 32 + kg * 8;
    bf16x8 aH[4], aL[4], bH[4], bL[4];
    #pragma unroll
    for (int m = 0; m < 4; ++m) {
      const size_t off = (size_t)(i0 + m * 16 + r16) * D_EMB + koff;
      aH[m] = *(const bf16x8*)(Mhi + off);
      aL[m] = *(const bf16x8*)(Mlo + off);
    }
    #pragma unroll
    for (int n = 0; n < 4; ++n) {
      const size_t off = (size_t)(j0 + n * 16 + r16) * D_EMB + koff;
      bH[n] = *(const bf16x8*)(Mhi + off);
      bL[n] = *(const bf16x8*)(Mlo + off);
    }
    #pragma unroll
    for (int m = 0; m < 4; ++m)
      #pragma unroll
      for (int n = 0; n < 4; ++n) {
        acc[m][n] = __builtin_amdgcn_mfma_f32_16x16x32_bf16(
            aH[m], bH[n], acc[m][n], 0, 0, 0);
        acc[m][n] = __builtin_amdgcn_mfma_f32_16x16x32_bf16(
            aH[m], bL[n], acc[m][n], 0, 0, 0);
        acc[m][n] = __builtin_amdgcn_mfma_f32_16x16x32_bf16(
            aL[m], bH[n], acc[m][n], 0, 0, 0);
      }
  }

  // ---- epilogue: distances + distortion partial sums (all static indices)
  float rB[4];
  #pragma unroll
  for (int n = 0; n < 4; ++n) rB[n] = nrm[j0 + n * 16 + r16];

  float s1 = 0.f, s2 = 0.f, s3 = 0.f, s4 = 0.f;
  #pragma unroll
  for (int m = 0; m < 4; ++m) {
    #pragma unroll
    for (int reg = 0; reg < 4; ++reg) {
      const int gr = i0 + m * 16 + kg * 4 + reg;   // C/D row for this reg
      const float rA = nrm[gr];
      const float* __restrict__ Drow = Dm + (size_t)gr * N_PTS;
      #pragma unroll
      for (int n = 0; n < 4; ++n) {
        const int gc = j0 + n * 16 + r16;          // C/D col
        const float Dv = Drow[gc];
        const float dot = acc[m][n][reg];
        const float sq = rA + rB[n] - 2.f * dot;
        float dd = (sq > 0.f) ? __builtin_amdgcn_sqrtf(sq) : 0.f;
        const bool diag = (gr == gc);
        if (diag) dd = 0.f;                        // exact: ||x-x|| = 0
        const float denom = Dv + (diag ? 1.f : 0.f) + 1e-8f;
        const float rd = __builtin_amdgcn_rcpf(denom);
        const float av = dd * rd;                  // a = d/denom
        const float bv = Dv * rd;                  // b = D/denom
        s1 += av;
        s2 = fmaf(av, av, s2);
        s3 = fmaf(av, bv, s3);
        s4 = fmaf(bv, bv, s4);
      }
    }
  }

  // ---- wave shuffle reduce, one contention-free f64 write per wave
  #pragma unroll
  for (int off = 32; off > 0; off >>= 1) {
    s1 += __shfl_down(s1, off);
    s2 += __shfl_down(s2, off);
    s3 += __shfl_down(s3, off);
    s4 += __shfl_down(s4, off);
  }
  if (l == 0) {
    const int gw = ((blockIdx.y * gridDim.x + blockIdx.x) << 2) + w;
    part[0 * NWAVE + gw] = (double)s1;
    part[1 * NWAVE + gw] = (double)s2;
    part[2 * NWAVE + gw] = (double)s3;
    part[3 * NWAVE + gw] = (double)s4;
  }
}

// ---------------------------------------------------------------------------
// Reduce 4 x NWAVE partials; emit sum(dist) = s^2*S2 - 2 s S3 + S4, s=S1/S2.
// ---------------------------------------------------------------------------
__global__ __launch_bounds__(1024) void distortion_final(
    const double* __restrict__ part, float* __restrict__ out) {
  __shared__ double red[16][4];
  const int t = threadIdx.x;
  double s[4];
  #pragma unroll
  for (int k = 0; k < 4; ++k) {
    double v = 0.0;
    #pragma unroll
    for (int c = 0; c < NWAVE / 1024; ++c) v += part[k * NWAVE + c * 1024 + t];
    s[k] = v;
  }
  #pragma unroll
  for (int off = 32; off > 0; off >>= 1)
    #pragma unroll
    for (int k = 0; k < 4; ++k) s[k] += __shfl_down(s[k], off);
  const int w = t >> 6, l = t & 63;
  if (l == 0) {
    #pragma unroll
    for (int k = 0; k < 4; ++k) red[w][k] = s[k];
  }
  __syncthreads();
  if (t == 0) {
    double S0 = 0, S1 = 0, S2 = 0, S3 = 0;
    #pragma unroll
    for (int ww = 0; ww < 16; ++ww) {
      S0 += red[ww][0]; S1 += red[ww][1]; S2 += red[ww][2]; S3 += red[ww][3];
    }
    const double sc = S0 / S1;
    const double r = (sc * sc * S1 - 2.0 * sc * S2 + S3) /
                     ((double)N_PTS * (double)N_PTS - (double)N_PTS);
    out[0] = (float)r;
  }
}

extern "C" void kernel_launch(void* const* d_in, const int* in_sizes, int n_in,
                              void* d_out, int out_size, void* d_ws, size_t ws_size,
                              hipStream_t stream) {
  const float* mapping = (const float*)d_in[0];
  const float* Dm = (const float*)d_in[1];
  float* out = (float*)d_out;
  // ws layout: nrm 16KB | part 128KB | Mhi 512KB | Mlo 512KB  (~1.2 MB)
  float* nrm = (float*)d_ws;
  double* part = (double*)((char*)d_ws + 16384);
  ushort* Mhi = (ushort*)((char*)d_ws + 16384 + 131072);
  ushort* Mlo = (ushort*)((char*)d_ws + 16384 + 131072 + 524288);

  split_kernel<<<dim3(N_PTS * D_EMB / 256), dim3(256), 0, stream>>>(mapping, Mhi, Mlo);
  row_norms_kernel<<<dim3(N_PTS), dim3(64), 0, stream>>>(mapping, nrm);
  distortion_main<<<dim3(N_PTS / TILE, N_PTS / TILE), dim3(256), 0, stream>>>(
      Mhi, Mlo, Dm, nrm, part);
  distortion_final<<<1, 1024, 0, stream>>>(part, out);
}